// Round 7
// baseline (828.179 us; speedup 1.0000x reference)
//
#include <hip/hip_runtime.h>
#include <hip/hip_bf16.h>
#include <math.h>

#define N_NODES_C 50000
#define N_EDGES_C 800000
#define DIM 512
#define NUM_GRAPHS_C 64
#define NUM_CLASSES_C 10

#define NROWT ((N_NODES_C + 127) / 128)              // 391 row-tiles
#define GEMM_BLOCKS (((NROWT * 4 + 31) / 32) * 32)   // 1568 (pad to swizzle group)

typedef short bf16x8 __attribute__((ext_vector_type(8)));
typedef float f32x4 __attribute__((ext_vector_type(4)));
typedef float f32x2 __attribute__((ext_vector_type(2)));
typedef unsigned u32x2 __attribute__((ext_vector_type(2)));

__device__ __forceinline__ float bf2f(short s) {
    return __uint_as_float(((unsigned)(unsigned short)s) << 16);
}
__device__ __forceinline__ short f2bf(float f) {
    unsigned u = __float_as_uint(f);
    u += 0x7FFF + ((u >> 16) & 1);  // RNE
    return (short)(u >> 16);
}
__device__ __forceinline__ float eluf(float v) {
    return v > 0.0f ? v : expm1f(v);
}
__device__ __forceinline__ unsigned f32x4_to_fp8(float a, float b, float c, float d) {
    int w = 0;
    w = __builtin_amdgcn_cvt_pk_fp8_f32(a, b, w, false);
    w = __builtin_amdgcn_cvt_pk_fp8_f32(c, d, w, true);
    return (unsigned)w;
}
__device__ __forceinline__ unsigned char f32_to_fp8(float v) {
    return (unsigned char)(__builtin_amdgcn_cvt_pk_fp8_f32(v, v, 0, false) & 0xff);
}
__device__ __forceinline__ void acc_fp8x8(float* acc, u32x2 w) {
    f32x2 a = __builtin_amdgcn_cvt_pk_f32_fp8((int)w[0], false);
    f32x2 b = __builtin_amdgcn_cvt_pk_f32_fp8((int)w[0], true);
    f32x2 c = __builtin_amdgcn_cvt_pk_f32_fp8((int)w[1], false);
    f32x2 d = __builtin_amdgcn_cvt_pk_f32_fp8((int)w[1], true);
    acc[0] += a[0]; acc[1] += a[1]; acc[2] += b[0]; acc[3] += b[1];
    acc[4] += c[0]; acc[5] += c[1]; acc[6] += d[0]; acc[7] += d[1];
}
// async global->LDS, 16B/lane; lds dest = (wave-uniform base) + lane*16
__device__ __forceinline__ void async16(const void* g, void* l) {
    __builtin_amdgcn_global_load_lds((const __attribute__((address_space(1))) void*)g,
                                     (__attribute__((address_space(3))) void*)l, 16, 0, 0);
}

// ---------------- CSR build ----------------

__global__ void k_hist(const int* __restrict__ src, int* __restrict__ cnt) {
    int e = blockIdx.x * blockDim.x + threadIdx.x;
    if (e < N_EDGES_C) atomicAdd(&cnt[src[e]], 1);
}

__global__ __launch_bounds__(1024)
void k_scan(const int* __restrict__ cnt, int* __restrict__ start,
            int* __restrict__ cursor, int n) {
    __shared__ int sh[1024];
    __shared__ int carry_s;
    if (threadIdx.x == 0) carry_s = 0;
    __syncthreads();
    for (int base = 0; base < n; base += 1024) {
        int i = base + threadIdx.x;
        int v = (i < n) ? cnt[i] : 0;
        sh[threadIdx.x] = v;
        __syncthreads();
        for (int ofs = 1; ofs < 1024; ofs <<= 1) {
            int t = (threadIdx.x >= (unsigned)ofs) ? sh[threadIdx.x - ofs] : 0;
            __syncthreads();
            sh[threadIdx.x] += t;
            __syncthreads();
        }
        int incl = sh[threadIdx.x];
        int carry = carry_s;
        if (i < n) {
            int ex = carry + incl - v;
            start[i] = ex;
            cursor[i] = ex;
        }
        __syncthreads();
        if (threadIdx.x == 1023) carry_s = carry + incl;
        __syncthreads();
    }
    if (threadIdx.x == 0) start[n] = carry_s;
}

__global__ void k_fill(const int* __restrict__ src, const int* __restrict__ dst,
                       int* __restrict__ cursor, int* __restrict__ ebuf) {
    int e = blockIdx.x * blockDim.x + threadIdx.x;
    if (e < N_EDGES_C) {
        int pos = atomicAdd(&cursor[src[e]], 1);
        ebuf[pos] = dst[e];
    }
}

__global__ __launch_bounds__(1024)
void k_cnt(const int* __restrict__ batch, int* __restrict__ cnt) {
    __shared__ int h[NUM_GRAPHS_C];
    if (threadIdx.x < NUM_GRAPHS_C) h[threadIdx.x] = 0;
    __syncthreads();
    int n = blockIdx.x * blockDim.x + threadIdx.x;
    if (n < N_NODES_C) {
        int g = batch[n];
        if ((unsigned)g < NUM_GRAPHS_C) atomicAdd(&h[g], 1);
    }
    __syncthreads();
    if (threadIdx.x < NUM_GRAPHS_C && h[threadIdx.x] > 0)
        atomicAdd(&cnt[threadIdx.x], h[threadIdx.x]);
}

// Weff[d,j] = sum_k sign[k,d] * Wp[k*128+col[k,d], j]   (fp32)
__global__ void k_weff(const float* __restrict__ Hm, const float* __restrict__ Wp,
                       float* __restrict__ Weff) {
    __shared__ int   scol[4];
    __shared__ float ssign[4];
    int d = blockIdx.x;
    int h = threadIdx.x;  // 128 threads
    for (int k = 0; k < 4; ++k) {
        float v = Hm[((size_t)k * DIM + d) * 128 + h];
        if (v != 0.0f) { scol[k] = h; ssign[k] = v; }
    }
    __syncthreads();
    for (int j = threadIdx.x; j < DIM; j += 128) {
        float acc = 0.0f;
#pragma unroll
        for (int k = 0; k < 4; ++k)
            acc += ssign[k] * Wp[(size_t)(k * 128 + scol[k]) * DIM + j];
        Weff[(size_t)d * DIM + j] = acc;
    }
}

// Wt[n][k] bf16, k-contiguous: k<512 -> Weff[k][n], k>=512 -> Ws[k-512][n]
__global__ void k_prepw(const float* __restrict__ Weff, const float* __restrict__ Ws,
                        short* __restrict__ Wt) {
    int n = blockIdx.x;
    for (int k = threadIdx.x; k < 2 * DIM; k += 256) {
        float v = (k < DIM) ? Weff[(size_t)k * DIM + n] : Ws[(size_t)(k - DIM) * DIM + n];
        Wt[(size_t)n * (2 * DIM) + k] = f2bf(v);
    }
}

// fp32 -> bf16 + fp8 shadow, 8 elems/thread
__global__ void k_cast(const float* __restrict__ x, short* __restrict__ xb,
                       unsigned char* __restrict__ xq) {
    int idx = blockIdx.x * blockDim.x + threadIdx.x;
    if (idx >= N_NODES_C * DIM / 8) return;
    const float* p = x + (size_t)idx * 8;
    float v[8];
    bf16x8 o;
#pragma unroll
    for (int j = 0; j < 8; ++j) { v[j] = p[j]; o[j] = f2bf(v[j]); }
    u32x2 q;
    q[0] = f32x4_to_fp8(v[0], v[1], v[2], v[3]);
    q[1] = f32x4_to_fp8(v[4], v[5], v[6], v[7]);
    *(bf16x8*)(xb + (size_t)idx * 8) = o;
    *(u32x2*)(xq + (size_t)idx * 8) = q;
}

// ---------------- aggregation: CSR gather (fp8 shadow) + mean/fallback ----------------
__global__ __launch_bounds__(256)
void k_gather_8(const unsigned char* __restrict__ Hq, const int* __restrict__ start,
                const int* __restrict__ ebuf, const short* __restrict__ fb,
                short* __restrict__ outb) {
    int n = blockIdx.x * 4 + (threadIdx.x >> 6);
    int l = threadIdx.x & 63;
    if (n >= N_NODES_C) return;
    int s = start[n], e = start[n + 1];
    float acc[8] = {0, 0, 0, 0, 0, 0, 0, 0};
    int i = s;
    if (i + 4 <= e) {
        int d0 = ebuf[i], d1 = ebuf[i + 1], d2 = ebuf[i + 2], d3 = ebuf[i + 3];
        for (; i + 8 <= e; i += 4) {
            int n0 = ebuf[i + 4], n1 = ebuf[i + 5], n2 = ebuf[i + 6], n3 = ebuf[i + 7];
            u32x2 w0 = *(const u32x2*)(Hq + (size_t)d0 * DIM + l * 8);
            u32x2 w1 = *(const u32x2*)(Hq + (size_t)d1 * DIM + l * 8);
            u32x2 w2 = *(const u32x2*)(Hq + (size_t)d2 * DIM + l * 8);
            u32x2 w3 = *(const u32x2*)(Hq + (size_t)d3 * DIM + l * 8);
            acc_fp8x8(acc, w0); acc_fp8x8(acc, w1);
            acc_fp8x8(acc, w2); acc_fp8x8(acc, w3);
            d0 = n0; d1 = n1; d2 = n2; d3 = n3;
        }
        {
            u32x2 w0 = *(const u32x2*)(Hq + (size_t)d0 * DIM + l * 8);
            u32x2 w1 = *(const u32x2*)(Hq + (size_t)d1 * DIM + l * 8);
            u32x2 w2 = *(const u32x2*)(Hq + (size_t)d2 * DIM + l * 8);
            u32x2 w3 = *(const u32x2*)(Hq + (size_t)d3 * DIM + l * 8);
            acc_fp8x8(acc, w0); acc_fp8x8(acc, w1);
            acc_fp8x8(acc, w2); acc_fp8x8(acc, w3);
            i += 4;
        }
    }
    for (; i < e; ++i) {
        int d0 = ebuf[i];
        u32x2 w0 = *(const u32x2*)(Hq + (size_t)d0 * DIM + l * 8);
        acc_fp8x8(acc, w0);
    }
    bf16x8 o;
    if (e > s) {
        float inv = 1.0f / (float)(e - s);
#pragma unroll
        for (int j = 0; j < 8; ++j) o[j] = f2bf(acc[j] * inv);
    } else {
        o = *(const bf16x8*)(fb + (size_t)n * DIM + l * 8);
    }
    *(bf16x8*)(outb + (size_t)n * DIM + l * 8) = o;
}

// ---------------- MFMA dual-GEMM, async-staged ----------------
// 128x128 tile, BK=64, 4 waves. global_load_lds width-16 staging into
// XOR-swizzled LDS (row stride 64 elems; chunk' = chunk ^ (row&7)).
// Grid: 1D, XCD-swizzled so the 4 col-tiles of a row-tile share an XCD.

__device__ __forceinline__ void gemm_core(const short* __restrict__ A1,
                                          const short* __restrict__ A2,
                                          const short* __restrict__ Wt,
                                          short* As, short* Bs,
                                          int row0, int col0,
                                          int wave, int lane, f32x4 (*acc)[4]) {
    const int wm = wave >> 1, wn = wave & 1;
    const int q = lane >> 4, t16 = lane & 15;
    const int lr8 = lane >> 3;      // row-within-8 for staging
    const int lcp = lane & 7;       // LDS chunk slot c'
    const int gch = lcp ^ lr8;      // global chunk c = c' ^ (r&7)
    for (int p = 0; p < 2; ++p) {
        const short* A = p ? A2 : A1;
        for (int kt = 0; kt < DIM; kt += 64) {
            __syncthreads();  // previous round's LDS reads done
#pragma unroll
            for (int j = 0; j < 4; ++j) {
                int rb = wave * 32 + j * 8;          // 8-row group base (wave-uniform)
                int r = rb + lr8;
                const short* ga = A + (size_t)(row0 + r) * DIM + kt + gch * 8;
                async16(ga, As + rb * 64);
                const short* gb = Wt + (size_t)(col0 + r) * (2 * DIM) + p * DIM + kt + gch * 8;
                async16(gb, Bs + rb * 64);
            }
            __syncthreads();  // staging drained (compiler emits vmcnt wait)
#pragma unroll
            for (int kh = 0; kh < 2; ++kh) {
                bf16x8 af[4], bfv[4];
#pragma unroll
                for (int mi = 0; mi < 4; ++mi) {
                    int r = wm * 64 + mi * 16 + t16;
                    int cp = (kh * 4 + q) ^ (t16 & 7);
                    af[mi] = *(const bf16x8*)(As + r * 64 + cp * 8);
                }
#pragma unroll
                for (int ni = 0; ni < 4; ++ni) {
                    int r = wn * 64 + ni * 16 + t16;
                    int cp = (kh * 4 + q) ^ (t16 & 7);
                    bfv[ni] = *(const bf16x8*)(Bs + r * 64 + cp * 8);
                }
#pragma unroll
                for (int mi = 0; mi < 4; ++mi)
#pragma unroll
                    for (int ni = 0; ni < 4; ++ni)
                        acc[mi][ni] = __builtin_amdgcn_mfma_f32_16x16x32_bf16(
                            af[mi], bfv[ni], acc[mi][ni], 0, 0, 0);
            }
        }
    }
}

__global__ __launch_bounds__(256)
void k_gemm_elu_mfma(const short* __restrict__ A1, const short* __restrict__ A2,
                     const short* __restrict__ Wt, const float* __restrict__ bias,
                     short* __restrict__ C, unsigned char* __restrict__ C8) {
    __shared__ __align__(16) short As[128 * 64];
    __shared__ __align__(16) short Bs[128 * 64];
    const int L = blockIdx.x;
    const int ct = (L & 31) >> 3;
    const int rt = ((L >> 5) << 3) + (L & 7);
    if (rt >= NROWT) return;
    const int row0 = rt * 128, col0 = ct * 128;
    const int tid = threadIdx.x;
    const int lane = tid & 63, wave = tid >> 6;
    const int wm = wave >> 1, wn = wave & 1;
    const int q = lane >> 4, t16 = lane & 15;
    f32x4 acc[4][4] = {};
    gemm_core(A1, A2, Wt, As, Bs, row0, col0, wave, lane, acc);
#pragma unroll
    for (int mi = 0; mi < 4; ++mi) {
        int rbase = row0 + wm * 64 + mi * 16 + q * 4;
#pragma unroll
        for (int ni = 0; ni < 4; ++ni) {
            int col = col0 + wn * 64 + ni * 16 + t16;
            float bj = bias[col];
#pragma unroll
            for (int r = 0; r < 4; ++r) {
                int row = rbase + r;
                if (row < N_NODES_C) {
                    float v = eluf(acc[mi][ni][r] + bj);
                    C[(size_t)row * DIM + col] = f2bf(v);
                    C8[(size_t)row * DIM + col] = f32_to_fp8(v);
                }
            }
        }
    }
}

__global__ __launch_bounds__(256)
void k_gemm_pool_mfma(const short* __restrict__ A1, const short* __restrict__ A2,
                      const short* __restrict__ Wt, const float* __restrict__ bias,
                      const int* __restrict__ batch, float* __restrict__ gsum) {
    __shared__ __align__(16) short As[128 * 64];
    __shared__ __align__(16) short Bs[128 * 64];
    __shared__ int sbatch[128];
    const int L = blockIdx.x;
    const int ct = (L & 31) >> 3;
    const int rt = ((L >> 5) << 3) + (L & 7);
    if (rt >= NROWT) return;
    const int row0 = rt * 128, col0 = ct * 128;
    const int tid = threadIdx.x;
    const int lane = tid & 63, wave = tid >> 6;
    const int wm = wave >> 1, wn = wave & 1;
    const int q = lane >> 4, t16 = lane & 15;
    if (tid < 128) {
        int rw = row0 + tid;
        sbatch[tid] = (rw < N_NODES_C) ? batch[rw] : -1;
    }
    f32x4 acc[4][4] = {};
    gemm_core(A1, A2, Wt, As, Bs, row0, col0, wave, lane, acc);
#pragma unroll
    for (int mi = 0; mi < 4; ++mi) {
        int rb = wm * 64 + mi * 16 + q * 4;
#pragma unroll
        for (int ni = 0; ni < 4; ++ni) {
            int col = col0 + wn * 64 + ni * 16 + t16;
            float bj = bias[col];
            int curg = -1;
            float run = 0.0f;
#pragma unroll
            for (int r = 0; r < 4; ++r) {
                int g = sbatch[rb + r];
                if (g < 0) break;
                float v = eluf(acc[mi][ni][r] + bj);
                if (g != curg) {
                    if (curg >= 0) atomicAdd(&gsum[(size_t)curg * DIM + col], run);
                    curg = g;
                    run = 0.0f;
                }
                run += v;
            }
            if (curg >= 0) atomicAdd(&gsum[(size_t)curg * DIM + col], run);
        }
    }
}

// out[g,j] = (gsum[g,:]/max(cnt[g],1)) @ Wc[:,j] + bc[j]
__global__ void k_final(const float* __restrict__ gsum, const int* __restrict__ cnt,
                        const float* __restrict__ Wc, const float* __restrict__ bc,
                        float* __restrict__ out) {
    int g = blockIdx.x;
    int j = threadIdx.x;
    if (j >= NUM_CLASSES_C) return;
    int c_ = cnt[g];
    float inv = 1.0f / (float)(c_ > 1 ? c_ : 1);
    float s = 0.0f;
    for (int c = 0; c < DIM; ++c)
        s += gsum[(size_t)g * DIM + c] * Wc[(size_t)c * NUM_CLASSES_C + j];
    out[g * NUM_CLASSES_C + j] = s * inv + bc[j];
}

// ---------------- launch ----------------

extern "C" void kernel_launch(void* const* d_in, const int* in_sizes, int n_in,
                              void* d_out, int out_size, void* d_ws, size_t ws_size,
                              hipStream_t stream) {
    const float* x   = (const float*)d_in[0];
    const int*   ei  = (const int*)d_in[1];
    const int*   src = ei;
    const int*   dst = ei + N_EDGES_C;
    const int* batch = (const int*)d_in[2];
    const float* Hm1 = (const float*)d_in[3];
    const float* Wp1 = (const float*)d_in[4];
    const float* Ws1 = (const float*)d_in[5];
    const float* b1  = (const float*)d_in[6];
    const float* Hm2 = (const float*)d_in[7];
    const float* Wp2 = (const float*)d_in[8];
    const float* Ws2 = (const float*)d_in[9];
    const float* b2  = (const float*)d_in[10];
    const float* Wc  = (const float*)d_in[11];
    const float* bc  = (const float*)d_in[12];
    float* out = (float*)d_out;

    char* ws = (char*)d_ws;
    size_t off = 0;
    auto alloc = [&](size_t bytes) {
        void* p = ws + off;
        off += (bytes + 255) & ~(size_t)255;
        return p;
    };
    const size_t nodeB16 = (size_t)N_NODES_C * DIM * 2;  // 51.2 MB
    const size_t nodeB8  = (size_t)N_NODES_C * DIM;      // 25.6 MB
    short* xb    = (short*)alloc(nodeB16);
    short* aggB  = (short*)alloc(nodeB16);
    short* hB    = (short*)alloc(nodeB16);
    unsigned char* xq = (unsigned char*)alloc(nodeB8);   // fp8 shadow of x
    unsigned char* hq = (unsigned char*)alloc(nodeB8);   // fp8 shadow of h1
    float* Weff1 = (float*)alloc((size_t)DIM * DIM * 4);
    float* Weff2 = (float*)alloc((size_t)DIM * DIM * 4);
    short* Wt1   = (short*)alloc((size_t)DIM * 2 * DIM * 2);
    short* Wt2   = (short*)alloc((size_t)DIM * 2 * DIM * 2);
    int*   cnt_i = (int*)alloc((size_t)N_NODES_C * 4);
    int*   start = (int*)alloc((size_t)(N_NODES_C + 1) * 4);
    int*   cursor= (int*)alloc((size_t)N_NODES_C * 4);
    int*   ebuf  = (int*)alloc((size_t)N_EDGES_C * 4);
    int*   cnt   = (int*)alloc((size_t)NUM_GRAPHS_C * 4);
    float* gsum  = (float*)alloc((size_t)NUM_GRAPHS_C * DIM * 4);

    hipMemsetAsync(cnt_i, 0, (size_t)N_NODES_C * 4, stream);
    hipMemsetAsync(cnt, 0, (size_t)NUM_GRAPHS_C * 4, stream);
    hipMemsetAsync(gsum, 0, (size_t)NUM_GRAPHS_C * DIM * 4, stream);

    // CSR build + weight prep + casts
    k_hist<<<(N_EDGES_C + 255) / 256, 256, 0, stream>>>(src, cnt_i);
    k_scan<<<1, 1024, 0, stream>>>(cnt_i, start, cursor, N_NODES_C);
    k_fill<<<(N_EDGES_C + 255) / 256, 256, 0, stream>>>(src, dst, cursor, ebuf);
    k_cnt<<<(N_NODES_C + 1023) / 1024, 1024, 0, stream>>>(batch, cnt);
    k_weff<<<DIM, 128, 0, stream>>>(Hm1, Wp1, Weff1);
    k_weff<<<DIM, 128, 0, stream>>>(Hm2, Wp2, Weff2);
    k_prepw<<<DIM, 256, 0, stream>>>(Weff1, Ws1, Wt1);
    k_prepw<<<DIM, 256, 0, stream>>>(Weff2, Ws2, Wt2);
    k_cast<<<(N_NODES_C * DIM / 8 + 255) / 256, 256, 0, stream>>>(x, xb, xq);

    // layer 1
    k_gather_8<<<(N_NODES_C + 3) / 4, 256, 0, stream>>>(xq, start, ebuf, xb, aggB);
    k_gemm_elu_mfma<<<GEMM_BLOCKS, 256, 0, stream>>>(aggB, xb, Wt1, b1, hB, hq);

    // layer 2
    k_gather_8<<<(N_NODES_C + 3) / 4, 256, 0, stream>>>(hq, start, ebuf, hB, aggB);
    k_gemm_pool_mfma<<<GEMM_BLOCKS, 256, 0, stream>>>(aggB, hB, Wt2, b2, batch, gsum);

    k_final<<<NUM_GRAPHS_C, 64, 0, stream>>>(gsum, cnt, Wc, bc, out);
}

// Round 8
// 776.102 us; speedup vs baseline: 1.0671x; 1.0671x over previous
//
#include <hip/hip_runtime.h>
#include <hip/hip_bf16.h>
#include <math.h>

#define N_NODES_C 50000
#define N_EDGES_C 800000
#define DIM 512
#define NUM_GRAPHS_C 64
#define NUM_CLASSES_C 10

#define NROWT ((N_NODES_C + 127) / 128)              // 391 row-tiles
#define GEMM_BLOCKS (((NROWT * 4 + 31) / 32) * 32)   // 1568 (pad to swizzle group)

typedef short bf16x8 __attribute__((ext_vector_type(8)));
typedef float f32x4 __attribute__((ext_vector_type(4)));
typedef float f32x2 __attribute__((ext_vector_type(2)));
typedef unsigned u32x2 __attribute__((ext_vector_type(2)));

__device__ __forceinline__ float bf2f(short s) {
    return __uint_as_float(((unsigned)(unsigned short)s) << 16);
}
__device__ __forceinline__ short f2bf(float f) {
    unsigned u = __float_as_uint(f);
    u += 0x7FFF + ((u >> 16) & 1);  // RNE
    return (short)(u >> 16);
}
__device__ __forceinline__ float eluf(float v) {
    return v > 0.0f ? v : expm1f(v);
}
__device__ __forceinline__ unsigned f32x4_to_fp8(float a, float b, float c, float d) {
    int w = 0;
    w = __builtin_amdgcn_cvt_pk_fp8_f32(a, b, w, false);
    w = __builtin_amdgcn_cvt_pk_fp8_f32(c, d, w, true);
    return (unsigned)w;
}
__device__ __forceinline__ unsigned char f32_to_fp8(float v) {
    return (unsigned char)(__builtin_amdgcn_cvt_pk_fp8_f32(v, v, 0, false) & 0xff);
}
__device__ __forceinline__ void acc_fp8x8(float* acc, u32x2 w) {
    f32x2 a = __builtin_amdgcn_cvt_pk_f32_fp8((int)w[0], false);
    f32x2 b = __builtin_amdgcn_cvt_pk_f32_fp8((int)w[0], true);
    f32x2 c = __builtin_amdgcn_cvt_pk_f32_fp8((int)w[1], false);
    f32x2 d = __builtin_amdgcn_cvt_pk_f32_fp8((int)w[1], true);
    acc[0] += a[0]; acc[1] += a[1]; acc[2] += b[0]; acc[3] += b[1];
    acc[4] += c[0]; acc[5] += c[1]; acc[6] += d[0]; acc[7] += d[1];
}

// ---------------- CSR build ----------------

__global__ void k_hist(const int* __restrict__ src, int* __restrict__ cnt) {
    int e = blockIdx.x * blockDim.x + threadIdx.x;
    if (e < N_EDGES_C) atomicAdd(&cnt[src[e]], 1);
}

__global__ __launch_bounds__(1024)
void k_scan(const int* __restrict__ cnt, int* __restrict__ start,
            int* __restrict__ cursor, int n) {
    __shared__ int sh[1024];
    __shared__ int carry_s;
    if (threadIdx.x == 0) carry_s = 0;
    __syncthreads();
    for (int base = 0; base < n; base += 1024) {
        int i = base + threadIdx.x;
        int v = (i < n) ? cnt[i] : 0;
        sh[threadIdx.x] = v;
        __syncthreads();
        for (int ofs = 1; ofs < 1024; ofs <<= 1) {
            int t = (threadIdx.x >= (unsigned)ofs) ? sh[threadIdx.x - ofs] : 0;
            __syncthreads();
            sh[threadIdx.x] += t;
            __syncthreads();
        }
        int incl = sh[threadIdx.x];
        int carry = carry_s;
        if (i < n) {
            int ex = carry + incl - v;
            start[i] = ex;
            cursor[i] = ex;
        }
        __syncthreads();
        if (threadIdx.x == 1023) carry_s = carry + incl;
        __syncthreads();
    }
    if (threadIdx.x == 0) start[n] = carry_s;
}

__global__ void k_fill(const int* __restrict__ src, const int* __restrict__ dst,
                       int* __restrict__ cursor, int* __restrict__ ebuf) {
    int e = blockIdx.x * blockDim.x + threadIdx.x;
    if (e < N_EDGES_C) {
        int pos = atomicAdd(&cursor[src[e]], 1);
        ebuf[pos] = dst[e];
    }
}

__global__ __launch_bounds__(1024)
void k_cnt(const int* __restrict__ batch, int* __restrict__ cnt) {
    __shared__ int h[NUM_GRAPHS_C];
    if (threadIdx.x < NUM_GRAPHS_C) h[threadIdx.x] = 0;
    __syncthreads();
    int n = blockIdx.x * blockDim.x + threadIdx.x;
    if (n < N_NODES_C) {
        int g = batch[n];
        if ((unsigned)g < NUM_GRAPHS_C) atomicAdd(&h[g], 1);
    }
    __syncthreads();
    if (threadIdx.x < NUM_GRAPHS_C && h[threadIdx.x] > 0)
        atomicAdd(&cnt[threadIdx.x], h[threadIdx.x]);
}

// Weff[d,j] = sum_k sign[k,d] * Wp[k*128+col[k,d], j]   (fp32)
__global__ void k_weff(const float* __restrict__ Hm, const float* __restrict__ Wp,
                       float* __restrict__ Weff) {
    __shared__ int   scol[4];
    __shared__ float ssign[4];
    int d = blockIdx.x;
    int h = threadIdx.x;  // 128 threads
    for (int k = 0; k < 4; ++k) {
        float v = Hm[((size_t)k * DIM + d) * 128 + h];
        if (v != 0.0f) { scol[k] = h; ssign[k] = v; }
    }
    __syncthreads();
    for (int j = threadIdx.x; j < DIM; j += 128) {
        float acc = 0.0f;
#pragma unroll
        for (int k = 0; k < 4; ++k)
            acc += ssign[k] * Wp[(size_t)(k * 128 + scol[k]) * DIM + j];
        Weff[(size_t)d * DIM + j] = acc;
    }
}

// Wt[n][k] bf16, k-contiguous: k<512 -> Weff[k][n], k>=512 -> Ws[k-512][n]
__global__ void k_prepw(const float* __restrict__ Weff, const float* __restrict__ Ws,
                        short* __restrict__ Wt) {
    int n = blockIdx.x;
    for (int k = threadIdx.x; k < 2 * DIM; k += 256) {
        float v = (k < DIM) ? Weff[(size_t)k * DIM + n] : Ws[(size_t)(k - DIM) * DIM + n];
        Wt[(size_t)n * (2 * DIM) + k] = f2bf(v);
    }
}

// fp32 -> bf16 + fp8 shadow, 8 elems/thread
__global__ void k_cast(const float* __restrict__ x, short* __restrict__ xb,
                       unsigned char* __restrict__ xq) {
    int idx = blockIdx.x * blockDim.x + threadIdx.x;
    if (idx >= N_NODES_C * DIM / 8) return;
    const float* p = x + (size_t)idx * 8;
    float v[8];
    bf16x8 o;
#pragma unroll
    for (int j = 0; j < 8; ++j) { v[j] = p[j]; o[j] = f2bf(v[j]); }
    u32x2 q;
    q[0] = f32x4_to_fp8(v[0], v[1], v[2], v[3]);
    q[1] = f32x4_to_fp8(v[4], v[5], v[6], v[7]);
    *(bf16x8*)(xb + (size_t)idx * 8) = o;
    *(u32x2*)(xq + (size_t)idx * 8) = q;
}

// ---------------- aggregation: CSR gather (fp8 shadow) + mean/fallback ----------------
__global__ __launch_bounds__(256)
void k_gather_8(const unsigned char* __restrict__ Hq, const int* __restrict__ start,
                const int* __restrict__ ebuf, const short* __restrict__ fb,
                short* __restrict__ outb) {
    int n = blockIdx.x * 4 + (threadIdx.x >> 6);
    int l = threadIdx.x & 63;
    if (n >= N_NODES_C) return;
    int s = start[n], e = start[n + 1];
    float acc[8] = {0, 0, 0, 0, 0, 0, 0, 0};
    int i = s;
    if (i + 4 <= e) {
        int d0 = ebuf[i], d1 = ebuf[i + 1], d2 = ebuf[i + 2], d3 = ebuf[i + 3];
        for (; i + 8 <= e; i += 4) {
            int n0 = ebuf[i + 4], n1 = ebuf[i + 5], n2 = ebuf[i + 6], n3 = ebuf[i + 7];
            u32x2 w0 = *(const u32x2*)(Hq + (size_t)d0 * DIM + l * 8);
            u32x2 w1 = *(const u32x2*)(Hq + (size_t)d1 * DIM + l * 8);
            u32x2 w2 = *(const u32x2*)(Hq + (size_t)d2 * DIM + l * 8);
            u32x2 w3 = *(const u32x2*)(Hq + (size_t)d3 * DIM + l * 8);
            acc_fp8x8(acc, w0); acc_fp8x8(acc, w1);
            acc_fp8x8(acc, w2); acc_fp8x8(acc, w3);
            d0 = n0; d1 = n1; d2 = n2; d3 = n3;
        }
        {
            u32x2 w0 = *(const u32x2*)(Hq + (size_t)d0 * DIM + l * 8);
            u32x2 w1 = *(const u32x2*)(Hq + (size_t)d1 * DIM + l * 8);
            u32x2 w2 = *(const u32x2*)(Hq + (size_t)d2 * DIM + l * 8);
            u32x2 w3 = *(const u32x2*)(Hq + (size_t)d3 * DIM + l * 8);
            acc_fp8x8(acc, w0); acc_fp8x8(acc, w1);
            acc_fp8x8(acc, w2); acc_fp8x8(acc, w3);
            i += 4;
        }
    }
    for (; i < e; ++i) {
        int d0 = ebuf[i];
        u32x2 w0 = *(const u32x2*)(Hq + (size_t)d0 * DIM + l * 8);
        acc_fp8x8(acc, w0);
    }
    bf16x8 o;
    if (e > s) {
        float inv = 1.0f / (float)(e - s);
#pragma unroll
        for (int j = 0; j < 8; ++j) o[j] = f2bf(acc[j] * inv);
    } else {
        o = *(const bf16x8*)(fb + (size_t)n * DIM + l * 8);
    }
    *(bf16x8*)(outb + (size_t)n * DIM + l * 8) = o;
}

// ---------------- MFMA dual-GEMM ----------------
// 128x128 tile, BK=64, 4 waves. VGPR-roundtrip staging (loads issued before the
// barrier -> overlap previous iteration's MFMAs) into XOR-swizzled LDS
// (row stride 64 elems, chunk' = chunk ^ (row&7) -> 0 bank conflicts).
// Grid: 1D, XCD-swizzled so the 4 col-tiles of a row-tile share an XCD.

__device__ __forceinline__ void gemm_core(const short* __restrict__ A1,
                                          const short* __restrict__ A2,
                                          const short* __restrict__ Wt,
                                          short* As, short* Bs,
                                          int row0, int col0,
                                          int wave, int lane, f32x4 (*acc)[4]) {
    const int wm = wave >> 1, wn = wave & 1;
    const int q = lane >> 4, t16 = lane & 15;
    const int tid = wave * 64 + lane;
    const int srow = tid >> 3;                  // 0..31
    const int gch = tid & 7;                    // global k-chunk 0..7
    for (int p = 0; p < 2; ++p) {
        const short* A = p ? A2 : A1;
        for (int kt = 0; kt < DIM; kt += 64) {
            // stage loads to VGPRs first: compiler hoists issue above the barrier,
            // overlapping latency with the previous iteration's MFMAs
            bf16x8 av[4], bv[4];
#pragma unroll
            for (int i = 0; i < 4; ++i) {
                int r = i * 32 + srow;
                int grow = row0 + r;
                if (grow < N_NODES_C)
                    av[i] = *(const bf16x8*)(A + (size_t)grow * DIM + kt + gch * 8);
                else
                    av[i] = (bf16x8){0, 0, 0, 0, 0, 0, 0, 0};
                bv[i] = *(const bf16x8*)(Wt + (size_t)(col0 + r) * (2 * DIM) + p * DIM + kt + gch * 8);
            }
            __syncthreads();  // previous round's LDS reads done
#pragma unroll
            for (int i = 0; i < 4; ++i) {
                int r = i * 32 + srow;
                int cp = gch ^ (r & 7);
                *(bf16x8*)(As + r * 64 + cp * 8) = av[i];
                *(bf16x8*)(Bs + r * 64 + cp * 8) = bv[i];
            }
            __syncthreads();
#pragma unroll
            for (int kh = 0; kh < 2; ++kh) {
                bf16x8 af[4], bfv[4];
#pragma unroll
                for (int mi = 0; mi < 4; ++mi) {
                    int r = wm * 64 + mi * 16 + t16;
                    int cp = (kh * 4 + q) ^ (t16 & 7);
                    af[mi] = *(const bf16x8*)(As + r * 64 + cp * 8);
                }
#pragma unroll
                for (int ni = 0; ni < 4; ++ni) {
                    int r = wn * 64 + ni * 16 + t16;
                    int cp = (kh * 4 + q) ^ (t16 & 7);
                    bfv[ni] = *(const bf16x8*)(Bs + r * 64 + cp * 8);
                }
#pragma unroll
                for (int mi = 0; mi < 4; ++mi)
#pragma unroll
                    for (int ni = 0; ni < 4; ++ni)
                        acc[mi][ni] = __builtin_amdgcn_mfma_f32_16x16x32_bf16(
                            af[mi], bfv[ni], acc[mi][ni], 0, 0, 0);
            }
        }
    }
}

__global__ __launch_bounds__(256)
void k_gemm_elu_mfma(const short* __restrict__ A1, const short* __restrict__ A2,
                     const short* __restrict__ Wt, const float* __restrict__ bias,
                     short* __restrict__ C, unsigned char* __restrict__ C8) {
    __shared__ __align__(16) short As[128 * 64];
    __shared__ __align__(16) short Bs[128 * 64];
    const int L = blockIdx.x;
    const int ct = (L & 31) >> 3;
    const int rt = ((L >> 5) << 3) + (L & 7);
    if (rt >= NROWT) return;
    const int row0 = rt * 128, col0 = ct * 128;
    const int tid = threadIdx.x;
    const int lane = tid & 63, wave = tid >> 6;
    const int wm = wave >> 1, wn = wave & 1;
    const int q = lane >> 4, t16 = lane & 15;
    f32x4 acc[4][4] = {};
    gemm_core(A1, A2, Wt, As, Bs, row0, col0, wave, lane, acc);
#pragma unroll
    for (int mi = 0; mi < 4; ++mi) {
        int rbase = row0 + wm * 64 + mi * 16 + q * 4;
#pragma unroll
        for (int ni = 0; ni < 4; ++ni) {
            int col = col0 + wn * 64 + ni * 16 + t16;
            float bj = bias[col];
#pragma unroll
            for (int r = 0; r < 4; ++r) {
                int row = rbase + r;
                if (row < N_NODES_C) {
                    float v = eluf(acc[mi][ni][r] + bj);
                    C[(size_t)row * DIM + col] = f2bf(v);
                    C8[(size_t)row * DIM + col] = f32_to_fp8(v);
                }
            }
        }
    }
}

__global__ __launch_bounds__(256)
void k_gemm_pool_mfma(const short* __restrict__ A1, const short* __restrict__ A2,
                      const short* __restrict__ Wt, const float* __restrict__ bias,
                      const int* __restrict__ batch, float* __restrict__ gsum) {
    __shared__ __align__(16) short As[128 * 64];
    __shared__ __align__(16) short Bs[128 * 64];
    __shared__ int sbatch[128];
    const int L = blockIdx.x;
    const int ct = (L & 31) >> 3;
    const int rt = ((L >> 5) << 3) + (L & 7);
    if (rt >= NROWT) return;
    const int row0 = rt * 128, col0 = ct * 128;
    const int tid = threadIdx.x;
    const int lane = tid & 63, wave = tid >> 6;
    const int wm = wave >> 1, wn = wave & 1;
    const int q = lane >> 4, t16 = lane & 15;
    if (tid < 128) {
        int rw = row0 + tid;
        sbatch[tid] = (rw < N_NODES_C) ? batch[rw] : -1;
    }
    f32x4 acc[4][4] = {};
    gemm_core(A1, A2, Wt, As, Bs, row0, col0, wave, lane, acc);
#pragma unroll
    for (int mi = 0; mi < 4; ++mi) {
        int rb = wm * 64 + mi * 16 + q * 4;
#pragma unroll
        for (int ni = 0; ni < 4; ++ni) {
            int col = col0 + wn * 64 + ni * 16 + t16;
            float bj = bias[col];
            int curg = -1;
            float run = 0.0f;
#pragma unroll
            for (int r = 0; r < 4; ++r) {
                int g = sbatch[rb + r];
                if (g < 0) break;
                float v = eluf(acc[mi][ni][r] + bj);
                if (g != curg) {
                    if (curg >= 0) atomicAdd(&gsum[(size_t)curg * DIM + col], run);
                    curg = g;
                    run = 0.0f;
                }
                run += v;
            }
            if (curg >= 0) atomicAdd(&gsum[(size_t)curg * DIM + col], run);
        }
    }
}

// out[g,j] = (gsum[g,:]/max(cnt[g],1)) @ Wc[:,j] + bc[j]
__global__ void k_final(const float* __restrict__ gsum, const int* __restrict__ cnt,
                        const float* __restrict__ Wc, const float* __restrict__ bc,
                        float* __restrict__ out) {
    int g = blockIdx.x;
    int j = threadIdx.x;
    if (j >= NUM_CLASSES_C) return;
    int c_ = cnt[g];
    float inv = 1.0f / (float)(c_ > 1 ? c_ : 1);
    float s = 0.0f;
    for (int c = 0; c < DIM; ++c)
        s += gsum[(size_t)g * DIM + c] * Wc[(size_t)c * NUM_CLASSES_C + j];
    out[g * NUM_CLASSES_C + j] = s * inv + bc[j];
}

// ---------------- launch ----------------

extern "C" void kernel_launch(void* const* d_in, const int* in_sizes, int n_in,
                              void* d_out, int out_size, void* d_ws, size_t ws_size,
                              hipStream_t stream) {
    const float* x   = (const float*)d_in[0];
    const int*   ei  = (const int*)d_in[1];
    const int*   src = ei;
    const int*   dst = ei + N_EDGES_C;
    const int* batch = (const int*)d_in[2];
    const float* Hm1 = (const float*)d_in[3];
    const float* Wp1 = (const float*)d_in[4];
    const float* Ws1 = (const float*)d_in[5];
    const float* b1  = (const float*)d_in[6];
    const float* Hm2 = (const float*)d_in[7];
    const float* Wp2 = (const float*)d_in[8];
    const float* Ws2 = (const float*)d_in[9];
    const float* b2  = (const float*)d_in[10];
    const float* Wc  = (const float*)d_in[11];
    const float* bc  = (const float*)d_in[12];
    float* out = (float*)d_out;

    char* ws = (char*)d_ws;
    size_t off = 0;
    auto alloc = [&](size_t bytes) {
        void* p = ws + off;
        off += (bytes + 255) & ~(size_t)255;
        return p;
    };
    const size_t nodeB16 = (size_t)N_NODES_C * DIM * 2;  // 51.2 MB
    const size_t nodeB8  = (size_t)N_NODES_C * DIM;      // 25.6 MB
    short* xb    = (short*)alloc(nodeB16);
    short* aggB  = (short*)alloc(nodeB16);
    short* hB    = (short*)alloc(nodeB16);
    unsigned char* xq = (unsigned char*)alloc(nodeB8);   // fp8 shadow of x
    unsigned char* hq = (unsigned char*)alloc(nodeB8);   // fp8 shadow of h1
    float* Weff1 = (float*)alloc((size_t)DIM * DIM * 4);
    float* Weff2 = (float*)alloc((size_t)DIM * DIM * 4);
    short* Wt1   = (short*)alloc((size_t)DIM * 2 * DIM * 2);
    short* Wt2   = (short*)alloc((size_t)DIM * 2 * DIM * 2);
    int*   cnt_i = (int*)alloc((size_t)N_NODES_C * 4);
    int*   start = (int*)alloc((size_t)(N_NODES_C + 1) * 4);
    int*   cursor= (int*)alloc((size_t)N_NODES_C * 4);
    int*   ebuf  = (int*)alloc((size_t)N_EDGES_C * 4);
    int*   cnt   = (int*)alloc((size_t)NUM_GRAPHS_C * 4);
    float* gsum  = (float*)alloc((size_t)NUM_GRAPHS_C * DIM * 4);

    hipMemsetAsync(cnt_i, 0, (size_t)N_NODES_C * 4, stream);
    hipMemsetAsync(cnt, 0, (size_t)NUM_GRAPHS_C * 4, stream);
    hipMemsetAsync(gsum, 0, (size_t)NUM_GRAPHS_C * DIM * 4, stream);

    // CSR build + weight prep + casts
    k_hist<<<(N_EDGES_C + 255) / 256, 256, 0, stream>>>(src, cnt_i);
    k_scan<<<1, 1024, 0, stream>>>(cnt_i, start, cursor, N_NODES_C);
    k_fill<<<(N_EDGES_C + 255) / 256, 256, 0, stream>>>(src, dst, cursor, ebuf);
    k_cnt<<<(N_NODES_C + 1023) / 1024, 1024, 0, stream>>>(batch, cnt);
    k_weff<<<DIM, 128, 0, stream>>>(Hm1, Wp1, Weff1);
    k_weff<<<DIM, 128, 0, stream>>>(Hm2, Wp2, Weff2);
    k_prepw<<<DIM, 256, 0, stream>>>(Weff1, Ws1, Wt1);
    k_prepw<<<DIM, 256, 0, stream>>>(Weff2, Ws2, Wt2);
    k_cast<<<(N_NODES_C * DIM / 8 + 255) / 256, 256, 0, stream>>>(x, xb, xq);

    // layer 1
    k_gather_8<<<(N_NODES_C + 3) / 4, 256, 0, stream>>>(xq, start, ebuf, xb, aggB);
    k_gemm_elu_mfma<<<GEMM_BLOCKS, 256, 0, stream>>>(aggB, xb, Wt1, b1, hB, hq);

    // layer 2
    k_gather_8<<<(N_NODES_C + 3) / 4, 256, 0, stream>>>(hq, start, ebuf, hB, aggB);
    k_gemm_pool_mfma<<<GEMM_BLOCKS, 256, 0, stream>>>(aggB, hB, Wt2, b2, batch, gsum);

    k_final<<<NUM_GRAPHS_C, 64, 0, stream>>>(gsum, cnt, Wc, bc, out);
}